// Round 5
// baseline (421.875 us; speedup 1.0000x reference)
//
#include <hip/hip_runtime.h>

typedef unsigned short u16;
typedef unsigned int u32;
typedef __attribute__((ext_vector_type(8))) short short8;
typedef __attribute__((ext_vector_type(4))) short short4_t;
typedef __attribute__((ext_vector_type(4))) float floatx4;
typedef __attribute__((ext_vector_type(4))) unsigned short ushort4_t;
typedef __attribute__((ext_vector_type(4))) float float4_t;
typedef __attribute__((ext_vector_type(2))) unsigned int uint2_t;

// ---- helpers ---------------------------------------------------------------

__device__ __forceinline__ u16 f2bf(float f) {
  unsigned u = __builtin_bit_cast(unsigned, f);
  u += 0x7FFFu + ((u >> 16) & 1u);   // RNE; inputs finite
  return (u16)(u >> 16);
}

// pack two fp32 -> bf16x2: lo16 = b, hi16 = a
__device__ __forceinline__ u32 pack_bf2(float a, float b) {
  u32 ua = __builtin_bit_cast(u32, a) + 0x8000u;
  u32 ub = __builtin_bit_cast(u32, b) + 0x8000u;
  return __builtin_amdgcn_perm(ua, ub, 0x07060302u);
}

// async global->LDS, 16B per lane. LDS dest must be wave-uniform base + lane*16.
__device__ __forceinline__ void gload_lds16(const void* g, void* l) {
  __builtin_amdgcn_global_load_lds(
      (const __attribute__((address_space(1))) void*)g,
      (__attribute__((address_space(3))) void*)l, 16, 0, 0);
}

// ---- prep kernels ----------------------------------------------------------

// X fp32 [8192][1024] -> bf16
__global__ void cvt_x(const float* __restrict__ src, u16* __restrict__ dst) {
  int i = blockIdx.x * 256 + threadIdx.x;
  float4_t f = ((const float4_t*)src)[i];
  ushort4_t u;
  u.x = f2bf(f.x); u.y = f2bf(f.y); u.z = f2bf(f.z); u.w = f2bf(f.w);
  ((ushort4_t*)dst)[i] = u;
}

// coalesced LDS-tiled transpose+cvt: W fp32 [K][N] -> bf16 [N][K].
__global__ __launch_bounds__(256) void transpose_cvt4(
    const float* __restrict__ wq, const float* __restrict__ wk,
    const float* __restrict__ wv, const float* __restrict__ wo,
    u16* __restrict__ qk, u16* __restrict__ vt, u16* __restrict__ ot, float sc) {
  __shared__ float T[64][65];
  const int which = blockIdx.z;
  const float* s = (which == 0) ? wq : (which == 1) ? wk : (which == 2) ? wv : wo;
  u16* d = (which == 0) ? qk : (which == 1) ? (qk + (1u << 20)) : (which == 2) ? vt : ot;
  const float scale = (which == 0) ? sc : 1.f;
  const int n0 = blockIdx.x * 64, k0 = blockIdx.y * 64;
  const int c = threadIdx.x & 63, rg = threadIdx.x >> 6;
  for (int i = 0; i < 16; ++i) {
    int r = i * 4 + rg;
    T[r][c] = s[(k0 + r) * 1024 + n0 + c];
  }
  __syncthreads();
  for (int i = 0; i < 16; ++i) {
    int r = i * 4 + rg;
    d[(n0 + r) * 1024 + k0 + c] = f2bf(T[c][r] * scale);
  }
}

// ---- bf16 MFMA GEMM: C[m][n] = sum_k A[m][k] * Bt[n][k] --------------------
template <int MODE>
__global__ __launch_bounds__(256) void gemm_bt(
    const u16* __restrict__ A, const u16* __restrict__ Bt, void* __restrict__ Cv,
    const float* __restrict__ bias, int K, int lda, int ldb, int ldc) {
  __shared__ u16 As[2][128 * 32];
  __shared__ u16 Bs[2][128 * 32];
  const int tid = threadIdx.x;
  const int w = tid >> 6, l = tid & 63, quad = l >> 4, l16 = l & 15;
  const int wm = w >> 1, wn = w & 1;
  const size_t m0 = (size_t)blockIdx.y * 128, n0 = (size_t)blockIdx.x * 128;

  floatx4 acc[4][4];
  for (int i = 0; i < 4; ++i)
    for (int j = 0; j < 4; ++j) acc[i][j] = (floatx4){0.f, 0.f, 0.f, 0.f};

  auto stage = [&](int k0, int buf) {
    for (int i = 0; i < 2; ++i) {
      int c = i * 256 + tid;
      int row = c >> 2, off = (c & 3) * 8;
      gload_lds16(A + (m0 + row) * (size_t)lda + k0 + off, &As[buf][c * 8]);
      gload_lds16(Bt + (n0 + row) * (size_t)ldb + k0 + off, &Bs[buf][c * 8]);
    }
  };

  const int nk = K >> 5;
  stage(0, 0);
  __syncthreads();

  for (int ki = 0; ki < nk; ++ki) {
    const int buf = ki & 1;
    if (ki + 1 < nk) stage((ki + 1) << 5, buf ^ 1);

    short8 a[4], bb[4];
    for (int im = 0; im < 4; ++im)
      a[im] = *(const short8*)&As[buf][(wm * 64 + im * 16 + l16) * 32 + quad * 8];
    for (int in = 0; in < 4; ++in)
      bb[in] = *(const short8*)&Bs[buf][(wn * 64 + in * 16 + l16) * 32 + quad * 8];
    for (int im = 0; im < 4; ++im)
      for (int in = 0; in < 4; ++in)
        acc[im][in] = __builtin_amdgcn_mfma_f32_16x16x32_bf16(a[im], bb[in], acc[im][in], 0, 0, 0);

    __syncthreads();
  }

  for (int im = 0; im < 4; ++im)
    for (int in = 0; in < 4; ++in) {
      size_t r0 = m0 + wm * 64 + im * 16 + quad * 4;
      size_t col = n0 + wn * 64 + in * 16 + l16;
      float bv = (MODE == 1) ? bias[col] : 0.f;
      for (int r = 0; r < 4; ++r) {
        float val = acc[im][in][r] + bv;
        if (MODE == 0)
          ((u16*)Cv)[(r0 + r) * (size_t)ldc + col] = f2bf(val);
        else
          ((float*)Cv)[(r0 + r) * (size_t)ldc + col] = val;
      }
    }
}

// ---- flash attention (causal, S^T form, registered P) ----------------------
// grid (64 bh, 16 y), qt = 15-y (longest blocks dispatched first).
// 1024 blocks = 4 blocks/CU resident. 256 thr = 4 waves; wave owns 32 q.
// QK: bf16 [8192][2048] (Q pre-scaled cols 0..1023, K cols 1024..2047).
// Vt: bf16 [1024][8192]. ctx: bf16 [8192][1024].
// S^T C-layout (col=l16=q, row=quad*4+r=kpos) IS the B-operand layout of
// 16x16x16 MFMA (k=quad*4+j) -> P stays in registers; PV: A=V^T from LDS.
// Swizzle: byte(row,col2B) = row*128 + ((2*col) ^ ((row&7)<<4)).
__global__ __launch_bounds__(256, 4) void flash_attn(
    const u16* __restrict__ QK, const u16* __restrict__ Vt, u16* __restrict__ ctx) {
  __shared__ u16 Ks[2][64 * 64];
  __shared__ u16 Vs[2][64 * 64];

  const int tid = threadIdx.x;
  const int w = tid >> 6, l = tid & 63, quad = l >> 4, l16 = l & 15;
  const int bh = blockIdx.x, qt = 15 - (int)blockIdx.y;
  const int b = bh >> 4, h = bh & 15;
  const int xr = (l16 & 7) << 4;

  const int q0w = qt * 128 + w * 32;
  const int nkt = 2 * qt + 2;
  const int ktmax_w = (q0w + 31) >> 6;   // last live k-tile for this wave

  auto stage = [&](int kt, int buf) {
    for (int i = 0; i < 2; ++i) {
      int c = i * 256 + tid;
      int row = c >> 3, scol = ((c & 7) ^ (row & 7)) << 3;
      gload_lds16(QK + (size_t)(b * 2048 + kt * 64 + row) * 2048 + 1024 + h * 64 + scol,
                  &Ks[buf][c * 8]);
      gload_lds16(Vt + (size_t)(h * 64 + row) * 8192 + b * 2048 + kt * 64 + scol,
                  &Vs[buf][c * 8]);
    }
  };

  stage(0, 0);

  // Q B-frags (softmax scale pre-folded into Wq)
  short8 aq[2][2];
  for (int qf = 0; qf < 2; ++qf) {
    const size_t base = (size_t)(b * 2048 + q0w + qf * 16 + l16) * 2048 + h * 64 + quad * 8;
    aq[qf][0] = *(const short8*)(QK + base);
    aq[qf][1] = *(const short8*)(QK + base + 32);
  }

  floatx4 o[2][4];
  float lsum[2] = {0.f, 0.f};
  for (int qf = 0; qf < 2; ++qf)
    for (int df = 0; df < 4; ++df) o[qf][df] = (floatx4){0.f, 0.f, 0.f, 0.f};

  __syncthreads();

  for (int kt = 0; kt < nkt; ++kt) {
    const int buf = kt & 1;
    if (kt + 1 < nkt) stage(kt + 1, buf ^ 1);   // prefetch overlaps compute

    if (kt <= ktmax_w) {
      const bool need_mask = (kt == ktmax_w);

      short8 ka[4][2];
      for (int nf = 0; nf < 4; ++nf) {
        const char* kb = (const char*)&Ks[buf][0] + (nf * 16 + l16) * 128;
        ka[nf][0] = *(const short8*)(kb + ((quad * 16) ^ xr));
        ka[nf][1] = *(const short8*)(kb + ((64 + quad * 16) ^ xr));
      }
      // V^T A-frags for K=16 MFMA: lane holds Vs[d=df*16+l16][kchunk*16+quad*4+j]
      short4_t va[4][4];
      for (int df = 0; df < 4; ++df) {
        const char* vb = (const char*)&Vs[buf][0] + (df * 16 + l16) * 128;
        for (int nf = 0; nf < 4; ++nf)
          va[nf][df] = *(const short4_t*)(vb + ((nf * 32 + quad * 8) ^ xr));
      }

      for (int qf = 0; qf < 2; ++qf) {
        floatx4 s[4];
        for (int nf = 0; nf < 4; ++nf) s[nf] = (floatx4){0.f, 0.f, 0.f, 0.f};
        for (int nf = 0; nf < 4; ++nf) {
          s[nf] = __builtin_amdgcn_mfma_f32_16x16x32_bf16(ka[nf][0], aq[qf][0], s[nf], 0, 0, 0);
          s[nf] = __builtin_amdgcn_mfma_f32_16x16x32_bf16(ka[nf][1], aq[qf][1], s[nf], 0, 0, 0);
        }
        if (need_mask) {
          int qpos = q0w + qf * 16 + l16;
          for (int nf = 0; nf < 4; ++nf)
            for (int r = 0; r < 4; ++r) {
              int kpos = kt * 64 + nf * 16 + quad * 4 + r;
              if (kpos > qpos) s[nf][r] = -1e30f;
            }
        }
        for (int nf = 0; nf < 4; ++nf) {
          float p0 = __builtin_amdgcn_exp2f(s[nf][0]);
          float p1 = __builtin_amdgcn_exp2f(s[nf][1]);
          float p2 = __builtin_amdgcn_exp2f(s[nf][2]);
          float p3 = __builtin_amdgcn_exp2f(s[nf][3]);
          lsum[qf] += (p0 + p1) + (p2 + p3);
          uint2_t pk;
          pk.x = pack_bf2(p1, p0);   // lo16 = p0 (j=0), hi = p1
          pk.y = pack_bf2(p3, p2);
          short4_t pb = __builtin_bit_cast(short4_t, pk);  // B-frag of 16x16x16
          for (int df = 0; df < 4; ++df)
            o[qf][df] = __builtin_amdgcn_mfma_f32_16x16x16bf16_1k(va[nf][df], pb, o[qf][df], 0, 0, 0);
        }
      }
    }
    __syncthreads();
  }

  // epilogue: o^T has q on lane axis (l16) same as lsum -> in-lane normalize
  for (int qf = 0; qf < 2; ++qf) {
    float t = lsum[qf];
    t += __shfl_xor(t, 16, 64);
    t += __shfl_xor(t, 32, 64);
    float inv = __builtin_amdgcn_rcpf(t);
    size_t row = (size_t)(b * 2048 + q0w + qf * 16 + l16);
    for (int df = 0; df < 4; ++df) {
      ushort4_t st;
      for (int r = 0; r < 4; ++r) st[r] = f2bf(o[qf][df][r] * inv);
      *(ushort4_t*)(ctx + row * 1024 + h * 64 + df * 16 + quad * 4) = st;
    }
  }
}

// ---- launch ----------------------------------------------------------------

extern "C" void kernel_launch(void* const* d_in, const int* in_sizes, int n_in,
                              void* d_out, int out_size, void* d_ws, size_t ws_size,
                              hipStream_t stream) {
  const float* X  = (const float*)d_in[0];
  const float* Wq = (const float*)d_in[1];
  const float* Wk = (const float*)d_in[2];
  const float* Wv = (const float*)d_in[3];
  const float* Wo = (const float*)d_in[4];
  const float* bo = (const float*)d_in[5];

  char* ws = (char*)d_ws;
  u16* Xb   = (u16*)(ws);                  // 16 MiB; later overwritten with ctx
  u16* WqkT = (u16*)(ws + (16u << 20));    // 4 MiB: [Wq^T(scaled) ; Wk^T]
  u16* WvT  = (u16*)(ws + (20u << 20));    // 2 MiB
  u16* WoT  = (u16*)(ws + (22u << 20));    // 2 MiB
  u16* QKb  = (u16*)(ws + (24u << 20));    // 32 MiB: [8192][2048]
  u16* Vt   = (u16*)(ws + (56u << 20));    // 16 MiB: [1024][8192]

  const float SC = 0.125f * 1.44269504088896340736f;  // 1/sqrt(64) * log2(e)

  cvt_x<<<8192, 256, 0, stream>>>(X, Xb);
  transpose_cvt4<<<dim3(16, 16, 4), 256, 0, stream>>>(Wq, Wk, Wv, Wo, WqkT, WvT, WoT, SC);

  // [Q K] = Xb @ [Wq Wk] : [8192][2048]
  gemm_bt<0><<<dim3(16, 64), 256, 0, stream>>>(Xb, WqkT, QKb, nullptr, 1024, 1024, 1024, 2048);
  // Vt = (Xb @ Wv)^T : [1024][8192]
  gemm_bt<0><<<dim3(64, 8), 256, 0, stream>>>(WvT, Xb, Vt, nullptr, 1024, 1024, 1024, 8192);

  // causal flash attention; ctx overwrites Xb
  flash_attn<<<dim3(64, 16), 256, 0, stream>>>(QKb, Vt, Xb);

  // out = ctx @ Wo + bo : fp32
  gemm_bt<1><<<dim3(8, 64), 256, 0, stream>>>(Xb, WoT, (float*)d_out, bo, 1024, 1024, 1024, 1024);
}

// Round 6
// 261.663 us; speedup vs baseline: 1.6123x; 1.6123x over previous
//
#include <hip/hip_runtime.h>

typedef unsigned short u16;
typedef unsigned int u32;
typedef __attribute__((ext_vector_type(8))) short short8;
typedef __attribute__((ext_vector_type(4))) short short4_t;
typedef __attribute__((ext_vector_type(4))) float floatx4;
typedef __attribute__((ext_vector_type(4))) unsigned short ushort4_t;
typedef __attribute__((ext_vector_type(4))) float float4_t;
typedef __attribute__((ext_vector_type(2))) unsigned int uint2_t;

// ---- helpers ---------------------------------------------------------------

__device__ __forceinline__ u16 f2bf(float f) {
  unsigned u = __builtin_bit_cast(unsigned, f);
  u += 0x7FFFu + ((u >> 16) & 1u);   // RNE; inputs finite
  return (u16)(u >> 16);
}

// pack two fp32 -> bf16x2: lo16 = b, hi16 = a
__device__ __forceinline__ u32 pack_bf2(float a, float b) {
  u32 ua = __builtin_bit_cast(u32, a) + 0x8000u;
  u32 ub = __builtin_bit_cast(u32, b) + 0x8000u;
  return __builtin_amdgcn_perm(ua, ub, 0x07060302u);
}

// async global->LDS, 16B per lane. LDS dest must be wave-uniform base + lane*16.
__device__ __forceinline__ void gload_lds16(const void* g, void* l) {
  __builtin_amdgcn_global_load_lds(
      (const __attribute__((address_space(1))) void*)g,
      (__attribute__((address_space(3))) void*)l, 16, 0, 0);
}

// ---- prep kernels ----------------------------------------------------------

// X fp32 [8192][1024] -> bf16
__global__ void cvt_x(const float* __restrict__ src, u16* __restrict__ dst) {
  int i = blockIdx.x * 256 + threadIdx.x;
  float4_t f = ((const float4_t*)src)[i];
  ushort4_t u;
  u.x = f2bf(f.x); u.y = f2bf(f.y); u.z = f2bf(f.z); u.w = f2bf(f.w);
  ((ushort4_t*)dst)[i] = u;
}

// coalesced LDS-tiled transpose+cvt: W fp32 [K][N] -> bf16 [N][K].
__global__ __launch_bounds__(256) void transpose_cvt4(
    const float* __restrict__ wq, const float* __restrict__ wk,
    const float* __restrict__ wv, const float* __restrict__ wo,
    u16* __restrict__ qk, u16* __restrict__ vt, u16* __restrict__ ot, float sc) {
  __shared__ float T[64][65];
  const int which = blockIdx.z;
  const float* s = (which == 0) ? wq : (which == 1) ? wk : (which == 2) ? wv : wo;
  u16* d = (which == 0) ? qk : (which == 1) ? (qk + (1u << 20)) : (which == 2) ? vt : ot;
  const float scale = (which == 0) ? sc : 1.f;
  const int n0 = blockIdx.x * 64, k0 = blockIdx.y * 64;
  const int c = threadIdx.x & 63, rg = threadIdx.x >> 6;
  for (int i = 0; i < 16; ++i) {
    int r = i * 4 + rg;
    T[r][c] = s[(k0 + r) * 1024 + n0 + c];
  }
  __syncthreads();
  for (int i = 0; i < 16; ++i) {
    int r = i * 4 + rg;
    d[(n0 + r) * 1024 + k0 + c] = f2bf(T[c][r] * scale);
  }
}

// ---- bf16 MFMA GEMM: C[m][n] = sum_k A[m][k] * Bt[n][k] --------------------
template <int MODE>
__global__ __launch_bounds__(256) void gemm_bt(
    const u16* __restrict__ A, const u16* __restrict__ Bt, void* __restrict__ Cv,
    const float* __restrict__ bias, int K, int lda, int ldb, int ldc) {
  __shared__ u16 As[2][128 * 32];
  __shared__ u16 Bs[2][128 * 32];
  const int tid = threadIdx.x;
  const int w = tid >> 6, l = tid & 63, quad = l >> 4, l16 = l & 15;
  const int wm = w >> 1, wn = w & 1;
  const size_t m0 = (size_t)blockIdx.y * 128, n0 = (size_t)blockIdx.x * 128;

  floatx4 acc[4][4];
  for (int i = 0; i < 4; ++i)
    for (int j = 0; j < 4; ++j) acc[i][j] = (floatx4){0.f, 0.f, 0.f, 0.f};

  auto stage = [&](int k0, int buf) {
    for (int i = 0; i < 2; ++i) {
      int c = i * 256 + tid;
      int row = c >> 2, off = (c & 3) * 8;
      gload_lds16(A + (m0 + row) * (size_t)lda + k0 + off, &As[buf][c * 8]);
      gload_lds16(Bt + (n0 + row) * (size_t)ldb + k0 + off, &Bs[buf][c * 8]);
    }
  };

  const int nk = K >> 5;
  stage(0, 0);
  __syncthreads();

  for (int ki = 0; ki < nk; ++ki) {
    const int buf = ki & 1;
    if (ki + 1 < nk) stage((ki + 1) << 5, buf ^ 1);

    short8 a[4], bb[4];
    for (int im = 0; im < 4; ++im)
      a[im] = *(const short8*)&As[buf][(wm * 64 + im * 16 + l16) * 32 + quad * 8];
    for (int in = 0; in < 4; ++in)
      bb[in] = *(const short8*)&Bs[buf][(wn * 64 + in * 16 + l16) * 32 + quad * 8];
    for (int im = 0; im < 4; ++im)
      for (int in = 0; in < 4; ++in)
        acc[im][in] = __builtin_amdgcn_mfma_f32_16x16x32_bf16(a[im], bb[in], acc[im][in], 0, 0, 0);

    __syncthreads();
  }

  for (int im = 0; im < 4; ++im)
    for (int in = 0; in < 4; ++in) {
      size_t r0 = m0 + wm * 64 + im * 16 + quad * 4;
      size_t col = n0 + wn * 64 + in * 16 + l16;
      float bv = (MODE == 1) ? bias[col] : 0.f;
      for (int r = 0; r < 4; ++r) {
        float val = acc[im][in][r] + bv;
        if (MODE == 0)
          ((u16*)Cv)[(r0 + r) * (size_t)ldc + col] = f2bf(val);
        else
          ((float*)Cv)[(r0 + r) * (size_t)ldc + col] = val;
      }
    }
}

// ---- flash attention (causal, S^T form, registered P) ----------------------
// grid (64 bh, 16 y), qt = 15-y (longest blocks dispatched first).
// 1024 blocks -> ~4 blocks/CU resident. 256 thr = 4 waves; wave owns 32 q.
// launch_bounds min-waves=2: DO NOT raise — (256,4) forced VGPR=64 and the
// kernel spilled to scratch (r5: WRITE_SIZE 16MB->373GB, flash 64->223us).
// QK: bf16 [8192][2048] (Q pre-scaled cols 0..1023, K cols 1024..2047).
// Vt: bf16 [1024][8192]. ctx: bf16 [8192][1024].
// S^T C-layout (col=l16=q, row=quad*4+r=kpos) IS the B-operand layout of
// 16x16x16 MFMA (k=quad*4+j) -> P stays in registers; PV: A=V^T from LDS.
// Swizzle: byte(row,col2B) = row*128 + ((2*col) ^ ((row&7)<<4)).
__global__ __launch_bounds__(256, 2) void flash_attn(
    const u16* __restrict__ QK, const u16* __restrict__ Vt, u16* __restrict__ ctx) {
  __shared__ u16 Ks[2][64 * 64];
  __shared__ u16 Vs[2][64 * 64];

  const int tid = threadIdx.x;
  const int w = tid >> 6, l = tid & 63, quad = l >> 4, l16 = l & 15;
  const int bh = blockIdx.x, qt = 15 - (int)blockIdx.y;
  const int b = bh >> 4, h = bh & 15;
  const int xr = (l16 & 7) << 4;

  const int q0w = qt * 128 + w * 32;
  const int nkt = 2 * qt + 2;
  const int ktmax_w = (q0w + 31) >> 6;   // last live k-tile for this wave

  auto stage = [&](int kt, int buf) {
    for (int i = 0; i < 2; ++i) {
      int c = i * 256 + tid;
      int row = c >> 3, scol = ((c & 7) ^ (row & 7)) << 3;
      gload_lds16(QK + (size_t)(b * 2048 + kt * 64 + row) * 2048 + 1024 + h * 64 + scol,
                  &Ks[buf][c * 8]);
      gload_lds16(Vt + (size_t)(h * 64 + row) * 8192 + b * 2048 + kt * 64 + scol,
                  &Vs[buf][c * 8]);
    }
  };

  stage(0, 0);

  // Q B-frags (softmax scale pre-folded into Wq)
  short8 aq[2][2];
  for (int qf = 0; qf < 2; ++qf) {
    const size_t base = (size_t)(b * 2048 + q0w + qf * 16 + l16) * 2048 + h * 64 + quad * 8;
    aq[qf][0] = *(const short8*)(QK + base);
    aq[qf][1] = *(const short8*)(QK + base + 32);
  }

  floatx4 o[2][4];
  float lsum[2] = {0.f, 0.f};
  for (int qf = 0; qf < 2; ++qf)
    for (int df = 0; df < 4; ++df) o[qf][df] = (floatx4){0.f, 0.f, 0.f, 0.f};

  __syncthreads();

  for (int kt = 0; kt < nkt; ++kt) {
    const int buf = kt & 1;
    if (kt + 1 < nkt) stage(kt + 1, buf ^ 1);   // prefetch overlaps compute

    if (kt <= ktmax_w) {
      const bool need_mask = (kt == ktmax_w);

      short8 ka[4][2];
      for (int nf = 0; nf < 4; ++nf) {
        const char* kb = (const char*)&Ks[buf][0] + (nf * 16 + l16) * 128;
        ka[nf][0] = *(const short8*)(kb + ((quad * 16) ^ xr));
        ka[nf][1] = *(const short8*)(kb + ((64 + quad * 16) ^ xr));
      }
      // V^T A-frags for K=16 MFMA: lane holds Vs[d=df*16+l16][kchunk*16+quad*4+j]
      short4_t va[4][4];
      for (int df = 0; df < 4; ++df) {
        const char* vb = (const char*)&Vs[buf][0] + (df * 16 + l16) * 128;
        for (int nf = 0; nf < 4; ++nf)
          va[nf][df] = *(const short4_t*)(vb + ((nf * 32 + quad * 8) ^ xr));
      }

      for (int qf = 0; qf < 2; ++qf) {
        floatx4 s[4];
        for (int nf = 0; nf < 4; ++nf) s[nf] = (floatx4){0.f, 0.f, 0.f, 0.f};
        for (int nf = 0; nf < 4; ++nf) {
          s[nf] = __builtin_amdgcn_mfma_f32_16x16x32_bf16(ka[nf][0], aq[qf][0], s[nf], 0, 0, 0);
          s[nf] = __builtin_amdgcn_mfma_f32_16x16x32_bf16(ka[nf][1], aq[qf][1], s[nf], 0, 0, 0);
        }
        if (need_mask) {
          int qpos = q0w + qf * 16 + l16;
          for (int nf = 0; nf < 4; ++nf)
            for (int r = 0; r < 4; ++r) {
              int kpos = kt * 64 + nf * 16 + quad * 4 + r;
              if (kpos > qpos) s[nf][r] = -1e30f;
            }
        }
        for (int nf = 0; nf < 4; ++nf) {
          float p0 = __builtin_amdgcn_exp2f(s[nf][0]);
          float p1 = __builtin_amdgcn_exp2f(s[nf][1]);
          float p2 = __builtin_amdgcn_exp2f(s[nf][2]);
          float p3 = __builtin_amdgcn_exp2f(s[nf][3]);
          lsum[qf] += (p0 + p1) + (p2 + p3);
          uint2_t pk;
          pk.x = pack_bf2(p1, p0);   // lo16 = p0 (j=0), hi = p1
          pk.y = pack_bf2(p3, p2);
          short4_t pb = __builtin_bit_cast(short4_t, pk);  // B-frag of 16x16x16
          for (int df = 0; df < 4; ++df)
            o[qf][df] = __builtin_amdgcn_mfma_f32_16x16x16bf16_1k(va[nf][df], pb, o[qf][df], 0, 0, 0);
        }
      }
    }
    __syncthreads();
  }

  // epilogue: o^T has q on lane axis (l16) same as lsum -> in-lane normalize
  for (int qf = 0; qf < 2; ++qf) {
    float t = lsum[qf];
    t += __shfl_xor(t, 16, 64);
    t += __shfl_xor(t, 32, 64);
    float inv = __builtin_amdgcn_rcpf(t);
    size_t row = (size_t)(b * 2048 + q0w + qf * 16 + l16);
    for (int df = 0; df < 4; ++df) {
      ushort4_t st;
      for (int r = 0; r < 4; ++r) st[r] = f2bf(o[qf][df][r] * inv);
      *(ushort4_t*)(ctx + row * 1024 + h * 64 + df * 16 + quad * 4) = st;
    }
  }
}

// ---- launch ----------------------------------------------------------------

extern "C" void kernel_launch(void* const* d_in, const int* in_sizes, int n_in,
                              void* d_out, int out_size, void* d_ws, size_t ws_size,
                              hipStream_t stream) {
  const float* X  = (const float*)d_in[0];
  const float* Wq = (const float*)d_in[1];
  const float* Wk = (const float*)d_in[2];
  const float* Wv = (const float*)d_in[3];
  const float* Wo = (const float*)d_in[4];
  const float* bo = (const float*)d_in[5];

  char* ws = (char*)d_ws;
  u16* Xb   = (u16*)(ws);                  // 16 MiB; later overwritten with ctx
  u16* WqkT = (u16*)(ws + (16u << 20));    // 4 MiB: [Wq^T(scaled) ; Wk^T]
  u16* WvT  = (u16*)(ws + (20u << 20));    // 2 MiB
  u16* WoT  = (u16*)(ws + (22u << 20));    // 2 MiB
  u16* QKb  = (u16*)(ws + (24u << 20));    // 32 MiB: [8192][2048]
  u16* Vt   = (u16*)(ws + (56u << 20));    // 16 MiB: [1024][8192]

  const float SC = 0.125f * 1.44269504088896340736f;  // 1/sqrt(64) * log2(e)

  cvt_x<<<8192, 256, 0, stream>>>(X, Xb);
  transpose_cvt4<<<dim3(16, 16, 4), 256, 0, stream>>>(Wq, Wk, Wv, Wo, WqkT, WvT, WoT, SC);

  // [Q K] = Xb @ [Wq Wk] : [8192][2048]
  gemm_bt<0><<<dim3(16, 64), 256, 0, stream>>>(Xb, WqkT, QKb, nullptr, 1024, 1024, 1024, 2048);
  // Vt = (Xb @ Wv)^T : [1024][8192]
  gemm_bt<0><<<dim3(64, 8), 256, 0, stream>>>(WvT, Xb, Vt, nullptr, 1024, 1024, 1024, 8192);

  // causal flash attention; ctx overwrites Xb
  flash_attn<<<dim3(64, 16), 256, 0, stream>>>(QKb, Vt, Xb);

  // out = ctx @ Wo + bo : fp32
  gemm_bt<1><<<dim3(8, 64), 256, 0, stream>>>(Xb, WoT, (float*)d_out, bo, 1024, 1024, 1024, 1024);
}